// Round 15
// baseline (260.334 us; speedup 1.0000x reference)
//
#include <hip/hip_runtime.h>
#include <hip/hip_bf16.h>

#define BATCH 8
#define CIN   128
#define HH    256
#define WW    256
#define OUTC  64
#define INCH  1152   // CIN*9
#define HW    (HH*WW)

#define PLANE_PX   ((size_t)HH * WW)                       // 65536 px
#define PLANE_B    (PLANE_PX * 16)                         // 1 MB per granule-plane
#define XG_BYTES   ((size_t)BATCH * 16 * PLANE_B)          // 128 MB
#define WMOD_BYTES ((size_t)BATCH * 9 * OUTC * CIN * 2)    // 1179648
#define Z_BYTES    64

typedef __attribute__((ext_vector_type(8)))  short short8;
typedef __attribute__((ext_vector_type(4)))  float f32x4;
typedef __attribute__((ext_vector_type(2)))  float f32x2;
typedef __attribute__((ext_vector_type(16))) float f32x16;
typedef __attribute__((ext_vector_type(4)))  unsigned int u32x4;

__device__ __forceinline__ unsigned short bf16r(float f) {
    unsigned u = __builtin_bit_cast(unsigned, f);
    u += 0x7fffu + ((u >> 16) & 1u);
    return (unsigned short)(u >> 16);
}

__device__ __forceinline__ void gload16(const void* src, void* dst_lds) {
    __builtin_amdgcn_global_load_lds(
        (const __attribute__((address_space(1))) unsigned int*)src,
        (__attribute__((address_space(3))) unsigned int*)dst_lds,
        16, 0, 0);
}

// Counted-vmcnt pair barrier: stage gload_lds (issued BEFORE the 18 A-loads)
// must be drained; the 18 A-loads stay in flight across the barrier (T4).
#define PBAR18()                                                        \
    do {                                                                \
        __builtin_amdgcn_sched_barrier(0);                              \
        asm volatile("s_waitcnt vmcnt(18) lgkmcnt(0)" ::: "memory");    \
        __builtin_amdgcn_sched_barrier(0);                              \
        __builtin_amdgcn_s_barrier();                                   \
        __builtin_amdgcn_sched_barrier(0);                              \
    } while (0)

// wmod[b][tap][o][c] = bf16(weight[o][c*9+tap] * style[b][c*9+tap])
__global__ void __launch_bounds__(256) wmod_kernel(const float* __restrict__ weight,
                                                   const float* __restrict__ style,
                                                   unsigned short* __restrict__ wmod) {
    int i = blockIdx.x * 256 + threadIdx.x;
    if (i >= BATCH * 9 * OUTC * CIN) return;
    int c    = i & (CIN - 1);
    int rest = i >> 7;
    int o    = rest & (OUTC - 1);
    int bt   = rest >> 6;
    int tap  = bt % 9;
    int b    = bt / 9;
    int k    = c * 9 + tap;
    wmod[i] = bf16r(weight[o * INCH + k] * style[b * INCH + k]);
}

// xG[b][p][px][c8]: granule-plane layout, p = c>>3 (16 planes of 1MB).
// Thread: 32 channels (cq) x 2 px; reads f32x2 lane-coalesced; writes 4 planes
// x 2 px x 16B (lane-contiguous coverage per plane).
__global__ void __launch_bounds__(256) repack_kernel(const float* __restrict__ x,
                                                     unsigned short* __restrict__ xG) {
    const int w2 = blockIdx.x * 128 + (threadIdx.x & 63) * 2;
    const int cq = threadIdx.x >> 6;       // 32-ch quarter
    const int h  = blockIdx.y;
    const int b  = blockIdx.z;

    const float* xp = x + ((size_t)(b * CIN + cq * 32)) * HW + h * WW + w2;

    f32x2 f[32];
#pragma unroll
    for (int j = 0; j < 32; ++j) f[j] = *(const f32x2*)(xp + (size_t)j * HW);

#pragma unroll
    for (int g = 0; g < 4; ++g) {
        int p = cq * 4 + g;
        unsigned short* op =
            xG + ((size_t)(b * 16 + p) * PLANE_PX + (size_t)h * WW + w2) * 8;
#pragma unroll
        for (int u = 0; u < 2; ++u) {
            unsigned pk[4];
#pragma unroll
            for (int d = 0; d < 4; ++d)
                pk[d] = (unsigned)bf16r(f[8 * g + 2 * d][u]) |
                        ((unsigned)bf16r(f[8 * g + 2 * d + 1][u]) << 16);
            u32x4 v = {pk[0], pk[1], pk[2], pk[3]};
            *(u32x4*)(op + u * 8) = v;
        }
    }
}

// conv11: granule-plane staging + counted-vmcnt pipeline.
// Block 256 = 4 waves; tile 64o x (8h x 32w); wave rows {2wv, 2wv+1}.
// Chunk = 16 ch (one 32x32x16 K) -> 8 chunks, 8-deep pipeline.
// LDS xs[2][2 granules][384 slots][16B] = 24.6 KB total. Stage: 3 gload_lds
// per thread (uniform), dest linear G = g2*384+s, source = plane (2k+g2) px
// CONTIGUOUS (1KB/instr full sectors). B-read: consecutive-16B ds_read_b128.
// Per chunk: stage(k+1) -> compute(k) [zero VMEM] -> loadA(k+1) -> PBAR18.
__global__ void __launch_bounds__(256, 2) conv11_kernel(
    const unsigned short* __restrict__ xG,
    const unsigned short* __restrict__ wmod,
    const unsigned short* __restrict__ zptr,
    float* __restrict__ out)
{
    __shared__ __align__(16) unsigned short xs_sm[2][2 * 384 * 8];

    const int tid = threadIdx.x;           // 0..255
    const int bx  = blockIdx.x;            // 0..255: ht*8 + wt
    const int b   = blockIdx.y;
    const int h0  = (bx >> 3) * 8;
    const int w0  = (bx & 7) * 32;

    const int wv    = tid >> 6;            // wave -> rows 2wv, 2wv+1
    const int l31   = tid & 31;
    const int ghalf = (tid >> 5) & 1;      // k-half (8 ch) of the 16-ch chunk

    // ---- stage geometry: 3 rounds, G = tid + i*256 in [0,768); g2 = G/384
    int  sg2[3];
    size_t spx[3];
    bool sok[3];
#pragma unroll
    for (int i = 0; i < 3; ++i) {
        int G  = tid + i * 256;
        int g2 = (G >= 384) ? 1 : 0;
        int s  = G - g2 * 384;
        int r   = s / 34;
        int col = s - r * 34;
        int h = h0 - 1 + r, w = w0 - 1 + col;
        sok[i] = (s < 340) && ((unsigned)h < HH) && ((unsigned)w < WW);
        sg2[i] = g2;
        spx[i] = (size_t)((h & 255) * WW + (w & 255)) * 16;  // byte off in plane
    }

    const char* xGb = (const char*)xG + (size_t)b * 16 * PLANE_B;
    const unsigned short* wmb = wmod + ((size_t)(b * 9) * OUTC) * CIN;

    short8 A[9][2];

    auto stage = [&](int k, int bufsel) {
        char* base = (char*)&xs_sm[bufsel][0];
#pragma unroll
        for (int i = 0; i < 3; ++i) {
            const void* src = sok[i]
                ? (const void*)(xGb + (size_t)(2 * k + sg2[i]) * PLANE_B + spx[i])
                : (const void*)zptr;
            gload16(src, base + (size_t)(tid + i * 256) * 16);
        }
    };

    auto loadA = [&](int k) {
        const unsigned short* wb = wmb + k * 16 + ghalf * 8;
#pragma unroll
        for (int tap = 0; tap < 9; ++tap)
#pragma unroll
            for (int mi = 0; mi < 2; ++mi)
                A[tap][mi] = *(const short8*)(
                    wb + ((size_t)tap * OUTC + mi * 32 + l31) * CIN);
    };

    f32x16 acc[2][2];
#pragma unroll
    for (int mi = 0; mi < 2; ++mi)
#pragma unroll
        for (int ni = 0; ni < 2; ++ni)
#pragma unroll
            for (int r = 0; r < 16; ++r) acc[mi][ni][r] = 0.f;

    auto compute = [&](int bufsel) {
        const unsigned short* buf = &xs_sm[bufsel][0];
        const int gb = ghalf * 384 * 8;    // short offset of this lane's granule plane
#pragma unroll
        for (int kh = 0; kh < 3; ++kh)
#pragma unroll
            for (int kw = 0; kw < 3; ++kw) {
                const int tap = kh * 3 + kw;
                short8 Bv[2];
#pragma unroll
                for (int ni = 0; ni < 2; ++ni) {
                    int s = (2 * wv + ni + kh) * 34 + l31 + kw;
                    Bv[ni] = *(const short8*)&buf[gb + s * 8];
                }
#pragma unroll
                for (int mi = 0; mi < 2; ++mi)
#pragma unroll
                    for (int ni = 0; ni < 2; ++ni)
                        acc[mi][ni] = __builtin_amdgcn_mfma_f32_32x32x16_bf16(
                            A[tap][mi], Bv[ni], acc[mi][ni], 0, 0, 0);
            }
    };

    // ---- prologue
    stage(0, 0);
    loadA(0);
    PBAR18();                              // drains stage(0); A(0) stays in flight

#pragma unroll
    for (int k = 0; k < 8; ++k) {
        if (k < 7) stage(k + 1, (k + 1) & 1);
        __builtin_amdgcn_sched_barrier(0);
        compute(k & 1);                    // zero VMEM inside
        __builtin_amdgcn_sched_barrier(0);
        if (k < 7) {
            loadA(k + 1);
            PBAR18();                      // drains stage(k+1); A(k+1) in flight
        }
    }

    // ---- epilogue: 32x32 D: col=lane&31, row=(r&3)+8*(r>>2)+4*ghalf
    float* op = out + ((size_t)b * OUTC) * HW + w0 + l31;
#pragma unroll
    for (int mi = 0; mi < 2; ++mi)
#pragma unroll
        for (int ni = 0; ni < 2; ++ni) {
            int h = h0 + 2 * wv + ni;
#pragma unroll
            for (int r = 0; r < 16; ++r) {
                int o = mi * 32 + (r & 3) + 8 * (r >> 2) + 4 * ghalf;
                op[(size_t)o * HW + h * WW] = acc[mi][ni][r];
            }
        }
}

// ---------------- fallback (round-14 conv10, proven) ----------------
#define PBARL()                                             \
    do {                                                    \
        asm volatile("s_waitcnt lgkmcnt(0)" ::: "memory");  \
        __builtin_amdgcn_sched_barrier(0);                  \
        __builtin_amdgcn_s_barrier();                       \
        __builtin_amdgcn_sched_barrier(0);                  \
    } while (0)

template <bool GW>
__global__ void __launch_bounds__(256, 2) conv10_kernel(
    const float* __restrict__ x,
    const unsigned short* __restrict__ wmod,
    const float* __restrict__ weight,
    const float* __restrict__ style,
    float* __restrict__ out)
{
    __shared__ __align__(16) unsigned short xs_sm[2][340 * 20];

    const int tid = threadIdx.x;
    const int bx  = blockIdx.x;
    const int b   = blockIdx.y;
    const int h0  = (bx >> 3) * 8;
    const int w0  = (bx & 7) * 32;

    const int wv  = tid >> 6;
    const int l31 = tid & 31;
    const int kh2 = (tid >> 5) & 1;

    const bool tv = tid < 200;
    const int tt  = tv ? tid : 0;
    const int cg  = tt / 100;
    const int rem = tt % 100;
    const int sr  = rem / 10;
    const int qw  = rem % 10;
    const int sh  = h0 - 1 + sr;
    const bool hok = tv && ((unsigned)sh < HH);
    const int wl  = w0 - 4 + qw * 4;
    const int wlc = min(max(wl, 0), WW - 4);
    const int colbase = wl - (w0 - 1);
    const float* xbase = x + ((size_t)(b * CIN + cg * 8)) * HW +
                         (hok ? sh : 0) * WW + wlc;

    f32x4  f[8];
    short8 A[9][2];

    auto loadG = [&](int chunk) {
        if (hok) {
#pragma unroll
            for (int j = 0; j < 8; ++j)
                f[j] = *(const f32x4*)(xbase + (size_t)(chunk * 16 + j) * HW);
        }
    };
    auto writeG = [&](unsigned short* buf) {
        if (tv) {
#pragma unroll
            for (int u = 0; u < 4; ++u) {
                int col = colbase + u;
                if (col >= 0 && col < 34) {
                    bool wok = hok && ((unsigned)(wl + u) < WW);
                    short8 sv;
#pragma unroll
                    for (int j = 0; j < 8; ++j)
                        sv[j] = wok ? (short)bf16r(f[j][u]) : (short)0;
                    int s = sr * 34 + col;
                    *(short8*)&buf[s * 20 + cg * 8] = sv;
                }
            }
        }
    };
    auto loadA = [&](int chunk) {
        if (GW) {
            const unsigned short* wb =
                wmod + ((size_t)(b * 9) * OUTC) * CIN + chunk * 16 + kh2 * 8;
#pragma unroll
            for (int tap = 0; tap < 9; ++tap)
#pragma unroll
                for (int mi = 0; mi < 2; ++mi)
                    A[tap][mi] = *(const short8*)(
                        wb + ((size_t)tap * OUTC + mi * 32 + l31) * CIN);
        } else {
#pragma unroll
            for (int tap = 0; tap < 9; ++tap)
#pragma unroll
                for (int mi = 0; mi < 2; ++mi) {
                    int o = mi * 32 + l31;
#pragma unroll
                    for (int j = 0; j < 8; ++j) {
                        int c = chunk * 16 + kh2 * 8 + j;
                        int k = c * 9 + tap;
                        A[tap][mi][j] = (short)bf16r(weight[o * INCH + k] *
                                                     style[b * INCH + k]);
                    }
                }
        }
    };

    f32x16 acc[2][2];
#pragma unroll
    for (int mi = 0; mi < 2; ++mi)
#pragma unroll
        for (int ni = 0; ni < 2; ++ni)
#pragma unroll
            for (int r = 0; r < 16; ++r) acc[mi][ni][r] = 0.f;

    auto compute = [&](const unsigned short* buf) {
#pragma unroll
        for (int kh = 0; kh < 3; ++kh)
#pragma unroll
            for (int kw = 0; kw < 3; ++kw) {
                const int tap = kh * 3 + kw;
                short8 Bv[2];
#pragma unroll
                for (int ni = 0; ni < 2; ++ni) {
                    int s = (2 * wv + ni + kh) * 34 + l31 + kw;
                    Bv[ni] = *(const short8*)&buf[s * 20 + kh2 * 8];
                }
#pragma unroll
                for (int mi = 0; mi < 2; ++mi)
#pragma unroll
                    for (int ni = 0; ni < 2; ++ni)
                        acc[mi][ni] = __builtin_amdgcn_mfma_f32_32x32x16_bf16(
                            A[tap][mi], Bv[ni], acc[mi][ni], 0, 0, 0);
            }
    };

    loadG(0);
    loadA(0);
    __builtin_amdgcn_sched_barrier(0);
    writeG(xs_sm[0]);
    PBARL();

#pragma unroll
    for (int k = 0; k < 8; ++k) {
        if (k < 7) loadG(k + 1);
        __builtin_amdgcn_sched_barrier(0);
        compute(xs_sm[k & 1]);
        __builtin_amdgcn_sched_barrier(0);
        if (k < 7) {
            loadA(k + 1);
            writeG(xs_sm[(k & 1) ^ 1]);
            PBARL();
        }
    }

    float* op = out + ((size_t)b * OUTC) * HW + w0 + l31;
#pragma unroll
    for (int mi = 0; mi < 2; ++mi)
#pragma unroll
        for (int ni = 0; ni < 2; ++ni) {
            int h = h0 + 2 * wv + ni;
#pragma unroll
            for (int r = 0; r < 16; ++r) {
                int o = mi * 32 + (r & 3) + 8 * (r >> 2) + 4 * kh2;
                op[(size_t)o * HW + h * WW] = acc[mi][ni][r];
            }
        }
}

extern "C" void kernel_launch(void* const* d_in, const int* in_sizes, int n_in,
                              void* d_out, int out_size, void* d_ws, size_t ws_size,
                              hipStream_t stream) {
    const float* x      = (const float*)d_in[0];
    const float* style  = (const float*)d_in[1];
    const float* weight = (const float*)d_in[2];
    float* out = (float*)d_out;

    const int wmod_total = BATCH * 9 * OUTC * CIN;

    if (ws_size >= XG_BYTES + WMOD_BYTES + Z_BYTES) {
        unsigned short* xG    = (unsigned short*)d_ws;
        unsigned short* wmodp = (unsigned short*)((char*)d_ws + XG_BYTES);
        unsigned short* zptr  = (unsigned short*)((char*)d_ws + XG_BYTES + WMOD_BYTES);

        wmod_kernel<<<(wmod_total + 255) / 256, 256, 0, stream>>>(weight, style, wmodp);
        hipMemsetAsync(zptr, 0, Z_BYTES, stream);
        repack_kernel<<<dim3(2, HH, BATCH), 256, 0, stream>>>(x, xG);
        conv11_kernel<<<dim3(256, BATCH), 256, 0, stream>>>(xG, wmodp, zptr, out);
    } else if (ws_size >= WMOD_BYTES) {
        unsigned short* wmodp = (unsigned short*)d_ws;
        wmod_kernel<<<(wmod_total + 255) / 256, 256, 0, stream>>>(weight, style, wmodp);
        conv10_kernel<true><<<dim3(256, BATCH), 256, 0, stream>>>(
            x, wmodp, nullptr, nullptr, out);
    } else {
        conv10_kernel<false><<<dim3(256, BATCH), 256, 0, stream>>>(
            x, nullptr, weight, style, out);
    }
}